// Round 7
// baseline (80.234 us; speedup 1.0000x reference)
//
#include <hip/hip_runtime.h>
#include <hip/hip_bf16.h>

#define B_SZ 256
#define NCH 64
#define NPOS 121
#define NPATCH (B_SZ * NPOS)      // 30976
#define KTOT 192
#define RGB_W 264                 // 88*3 ints per image row
#define LDR 264                   // LDS image row stride (shorts)
#define LDB 200                   // LDS B row stride (shorts), 400 B (16B-aligned)
#define FST 68                    // feats-bits row stride (words), 272 B (16B-aligned)
#define CROWS 48                  // image rows staged per conv block

typedef short bf16x8 __attribute__((ext_vector_type(8)));
typedef float f32x4 __attribute__((ext_vector_type(4)));

// round-to-nearest-even f32 -> bf16 (finite inputs)
static __device__ inline unsigned f2bf(float x) {
  union { float f; unsigned u; } a; a.f = x;
  return (a.u + 0x7FFFu + ((a.u >> 16) & 1u)) >> 16;
}
static __device__ inline unsigned pack2(float lo, float hi) {
  return f2bf(lo) | (f2bf(hi) << 16);
}

// ---------------------------------------------------------------------------
// conv: 512 blocks (2 per CU), 256 threads (4 waves). Block = (batch, half):
// half 0 -> patches 0..63   (image rows  0..47)
// half 1 -> patches 64..120 (image rows 40..87)
// Stride-8 8x8 conv: K-slice k0 = ks*32+lg*8 (mult of 8, k%24 in {0,8,16})
// never crosses a ky row -> A-frag is a contiguous 16B slice of the image.
// ---------------------------------------------------------------------------
__global__ __launch_bounds__(256) void conv_mfma(
    const int* __restrict__ rgb, const float* __restrict__ Wc,
    const float* __restrict__ bc, float* __restrict__ out) {
  __shared__ __align__(16) unsigned short imgL[CROWS * LDR];  // 25.3 KB
  __shared__ __align__(16) unsigned short BtL[NCH * LDB];     // 25.6 KB

  const int blk = blockIdx.x;
  const int b = blk >> 1, half = blk & 1;
  const int tid = threadIdx.x, lane = tid & 63, w = tid >> 6;   // 4 waves
  const int lr = lane & 15, lg = lane >> 4;
  const int rowbase = half ? 40 : 0;
  const int pbase = half ? 64 : 0;

  // bias early
  float bias[4];
  #pragma unroll
  for (int ni = 0; ni < 4; ++ni) bias[ni] = bc[ni * 16 + lr];

  // ---- rgb deep loads first: 48 rows * 66 int4 = 3168 = 12*256 + 96
  const int4* src4 = (const int4*)(rgb + ((size_t)b * 88 + rowbase) * RGB_W);
  int4 r[12];
  #pragma unroll
  for (int it = 0; it < 12; ++it) r[it] = src4[tid + it * 256];
  int4 rt;
  const bool tail = (tid < 96);
  if (tail) rt = src4[3072 + tid];

  // ---- B: Wc[k][n] f32 -> BtL[n][k] bf16. Wave w owns k in [w*48, w*48+48).
  #pragma unroll
  for (int j = 0; j < 24; ++j) {
    const int k = w * 48 + 2 * j;
    *(unsigned*)&BtL[lane * LDB + k] =
        pack2(Wc[k * NCH + lane], Wc[(k + 1) * NCH + lane]);
  }

  // ---- convert + write image to LDS as bf16 [48][264]
  #pragma unroll
  for (int it = 0; it < 12; ++it) {
    const int i = tid + it * 256;
    const int e = i * 4, row = e / RGB_W, col = e - row * RGB_W;
    uint2 p;
    p.x = pack2((float)r[it].x * (1.f/255.f), (float)r[it].y * (1.f/255.f));
    p.y = pack2((float)r[it].z * (1.f/255.f), (float)r[it].w * (1.f/255.f));
    *(uint2*)&imgL[row * LDR + col] = p;
  }
  if (tail) {
    const int i = 3072 + tid;
    const int e = i * 4, row = e / RGB_W, col = e - row * RGB_W;
    uint2 p;
    p.x = pack2((float)rt.x * (1.f/255.f), (float)rt.y * (1.f/255.f));
    p.y = pack2((float)rt.z * (1.f/255.f), (float)rt.w * (1.f/255.f));
    *(uint2*)&imgL[row * LDR + col] = p;
  }
  __syncthreads();

  // ---- MFMA: wave w owns patches pbase + w*16 .. +15, full N=64, K=192
  const int p = pbase + w * 16 + lr;
  const int pe = p > 120 ? 120 : p;          // pad rows duplicate row 120
  const int oy = pe / 11, ox = pe - oy * 11;
  f32x4 acc[4] = {};
  #pragma unroll
  for (int ks = 0; ks < 6; ++ks) {
    const int k0 = ks * 32 + lg * 8;
    const int ky = k0 / 24, km = k0 - ky * 24;
    const bf16x8 a =
        *(const bf16x8*)&imgL[(oy * 8 + ky - rowbase) * LDR + ox * 24 + km];
    #pragma unroll
    for (int ni = 0; ni < 4; ++ni) {
      const bf16x8 bb = *(const bf16x8*)&BtL[(ni * 16 + lr) * LDB + k0];
      acc[ni] = __builtin_amdgcn_mfma_f32_16x16x32_bf16(a, bb, acc[ni], 0, 0, 0);
    }
  }

  // ---- epilogue: +bias, relu (+0 kills -0), store
  float* outB = out + (size_t)b * NPOS * NCH;
  #pragma unroll
  for (int rr = 0; rr < 4; ++rr) {
    const int ps = pbase + w * 16 + lg * 4 + rr;
    if (ps < NPOS) {
      #pragma unroll
      for (int ni = 0; ni < 4; ++ni) {
        const float v = fmaxf(acc[ni][rr] + bias[ni], 0.f) + 0.f;
        outB[ps * NCH + ni * 16 + lr] = v;
      }
    }
  }
}

// ---------------------------------------------------------------------------
// guide: one block per batch, 256 threads. Atomic-free signature counts,
// exact verify on collision (~never taken), parallel allow rule.
// ---------------------------------------------------------------------------
__global__ __launch_bounds__(256) void guide(
    const float* __restrict__ feats, float* __restrict__ gout) {
  __shared__ __align__(16) unsigned fbits[NPOS * FST];  // 32.9 KB
  __shared__ unsigned sig[NPOS];
  __shared__ int counts[NPOS];
  __shared__ int redi[4];
  __shared__ float redf[4];

  const int b = blockIdx.x, tid = threadIdx.x;
  const int lane = tid & 63, w = tid >> 6;   // 4 waves

  // ---- load feats bits: 121*16 = 1936 uint4 = 7*256 + 144
  const uint4* src = (const uint4*)(feats + (size_t)b * NPOS * NCH);
  uint4 v[7];
  #pragma unroll
  for (int it = 0; it < 7; ++it) v[it] = src[tid + it * 256];
  uint4 vt;
  const bool tail = (tid < 144);
  if (tail) vt = src[1792 + tid];
  #pragma unroll
  for (int it = 0; it < 7; ++it) {
    const int g = tid + it * 256, row = g >> 4, q = g & 15;
    *(uint4*)&fbits[row * FST + q * 4] = v[it];
  }
  if (tail) {
    const int g = 1792 + tid, row = g >> 4, q = g & 15;
    *(uint4*)&fbits[row * FST + q * 4] = vt;
  }
  __syncthreads();

  // ---- per-row signature (own-row hash)
  if (tid < NPOS) {
    const uint4* fr = (const uint4*)&fbits[tid * FST];
    unsigned h = 0;
    #pragma unroll
    for (int q = 0; q < 16; ++q) {
      const uint4 u = fr[q];
      h ^= (u.x ^ (u.x >> 15)) * ((8u*q + 1u) * 0x9E3779B9u);
      h ^= (u.y ^ (u.y >> 15)) * ((8u*q + 3u) * 0x9E3779B9u);
      h ^= (u.z ^ (u.z >> 15)) * ((8u*q + 5u) * 0x9E3779B9u);
      h ^= (u.w ^ (u.w >> 15)) * ((8u*q + 7u) * 0x9E3779B9u);
    }
    sig[tid] = h;
  }
  __syncthreads();

  // ---- counts via signature match (exact verify on collision)
  int cnt = 0x7fffffff;
  if (tid < NPOS) {
    const unsigned si = sig[tid];
    int m = 0;
    for (int j = 0; j < NPOS; ++j) m += (sig[j] == si) ? 1 : 0;
    cnt = 1;
    if (m > 1) {
      cnt = 0;
      for (int j = 0; j < NPOS; ++j) {
        if (sig[j] == si) {
          int eq = 1;
          for (int c = 0; c < NCH; ++c) eq &= (fbits[tid*FST + c] == fbits[j*FST + c]);
          cnt += eq;
        }
      }
    }
    counts[tid] = cnt;
  }
  // kmin (block reduce over 4 waves)
  int km_ = cnt;
  #pragma unroll
  for (int m = 1; m < 64; m <<= 1) km_ = min(km_, __shfl_xor(km_, m, 64));
  if (lane == 0) redi[w] = km_;
  __syncthreads();
  int kmin = min(min(redi[0], redi[1]), min(redi[2], redi[3]));

  // ---- allow rule: cum[c_i] = #{j: counts[j] <= c_i}
  float wv = 0.f;
  if (tid < NPOS) {
    int cum = 0;
    for (int j = 0; j < NPOS; ++j) cum += (counts[j] <= cnt) ? 1 : 0;
    if (cum <= 36 || cnt == kmin) wv = 1.f / (float)cnt;   // K = int(0.3*121)
  }
  float s = wv;
  #pragma unroll
  for (int m = 1; m < 64; m <<= 1) s += __shfl_xor(s, m, 64);
  if (lane == 0) redf[w] = s;
  __syncthreads();
  const float Z = redf[0] + redf[1] + redf[2] + redf[3];
  if (tid < NPOS) gout[(size_t)b * NPOS + tid] = wv / Z;
}

extern "C" void kernel_launch(void* const* d_in, const int* in_sizes, int n_in,
                              void* d_out, int out_size, void* d_ws, size_t ws_size,
                              hipStream_t stream) {
  const int*   rgb = (const int*)d_in[0];
  const float* Wc  = (const float*)d_in[1];
  const float* bc  = (const float*)d_in[2];
  float* out   = (float*)d_out;                        // vis_op: 30976 x 64
  float* guide_o = out + (size_t)NPATCH * NCH;         // guidance: 256 x 121

  conv_mfma<<<2 * B_SZ, 256, 0, stream>>>(rgb, Wc, bc, out);
  guide<<<B_SZ, 256, 0, stream>>>(out, guide_o);
}

// Round 8
// 77.531 us; speedup vs baseline: 1.0349x; 1.0349x over previous
//
#include <hip/hip_runtime.h>
#include <hip/hip_bf16.h>

#define B_SZ 256
#define NCH 64
#define NPOS 121
#define NPATCH (B_SZ * NPOS)      // 30976
#define KTOT 192
#define RGB_W 264                 // 88*3 ints per image row
#define LDR 264                   // LDS image row stride (shorts), 528 B
#define LDB 200                   // LDS B row stride (shorts), 400 B (16B-aligned)
#define FST 68                    // feats-bits row stride (words)

typedef short bf16x8 __attribute__((ext_vector_type(8)));
typedef float f32x4 __attribute__((ext_vector_type(4)));

// round-to-nearest-even f32 -> bf16 (finite inputs)
static __device__ inline unsigned f2bf(float x) {
  union { float f; unsigned u; } a; a.f = x;
  return (a.u + 0x7FFFu + ((a.u >> 16) & 1u)) >> 16;
}
static __device__ inline unsigned pack2(float lo, float hi) {
  return f2bf(lo) | (f2bf(hi) << 16);
}

// ---------------------------------------------------------------------------
// One block per batch, 512 threads (8 waves).
// conv (MFMA, no im2col) + bias + relu + full guidance, single launch.
// Best-measured configuration (round 4: 78.06 us).
// ---------------------------------------------------------------------------
__global__ __launch_bounds__(512) void fused(
    const int* __restrict__ rgb, const float* __restrict__ Wc,
    const float* __restrict__ bc, float* __restrict__ out,
    float* __restrict__ gout) {
  __shared__ __align__(16) unsigned short rgbL[88 * LDR];  // 46.5 KB (aliased later)
  __shared__ __align__(16) unsigned short BtL[NCH * LDB];  // 25.6 KB
  __shared__ unsigned sig[NPOS];
  __shared__ int counts[NPOS];
  __shared__ int redi[8];
  __shared__ float redf[8];
  unsigned* fbits = (unsigned*)rgbL;   // [NPOS][FST] words = 32.9 KB < 46.5 KB

  const int b = blockIdx.x, tid = threadIdx.x;
  const int lane = tid & 63, w = tid >> 6;   // 8 waves
  const int lr = lane & 15, lg = lane >> 4;

  // ---- B: Wc[k][n] f32 -> BtL[n][k] bf16. Wave w owns k in [w*24, w*24+24).
  // Global reads coalesced in n (lane); paired k -> one aligned b32 LDS write.
  {
    #pragma unroll
    for (int j = 0; j < 12; ++j) {
      const int k = w * 24 + 2 * j;
      const float w0 = Wc[k * NCH + lane];
      const float w1 = Wc[(k + 1) * NCH + lane];
      *(unsigned*)&BtL[lane * LDB + k] = pack2(w0, w1);
    }
  }

  // ---- rgb staging, deep MLP: 5808 int4 = 11*512 + 176. Issue all loads
  // back-to-back into registers (static indices), then convert + LDS write.
  const int4* src4 = (const int4*)(rgb + (size_t)b * 88 * RGB_W);
  int4 r[11];
  #pragma unroll
  for (int it = 0; it < 11; ++it) r[it] = src4[tid + it * 512];
  int4 rt;
  const bool tail = (tid < 176);
  if (tail) rt = src4[5632 + tid];
  #pragma unroll
  for (int it = 0; it < 11; ++it) {
    const int i = tid + it * 512;
    const int e = i * 4, row = e / RGB_W, col = e - row * RGB_W;
    uint2 p;
    p.x = pack2((float)r[it].x * (1.f/255.f), (float)r[it].y * (1.f/255.f));
    p.y = pack2((float)r[it].z * (1.f/255.f), (float)r[it].w * (1.f/255.f));
    *(uint2*)&rgbL[row * LDR + col] = p;
  }
  if (tail) {
    const int i = 5632 + tid;
    const int e = i * 4, row = e / RGB_W, col = e - row * RGB_W;
    uint2 p;
    p.x = pack2((float)rt.x * (1.f/255.f), (float)rt.y * (1.f/255.f));
    p.y = pack2((float)rt.z * (1.f/255.f), (float)rt.w * (1.f/255.f));
    *(uint2*)&rgbL[row * LDR + col] = p;
  }
  __syncthreads();

  // ---- MFMA: wave w owns patch rows w*16..w*16+15, full N=64, K=192.
  // K-slice k0 = ks*32+lg*8 is a multiple of 8 -> never crosses a ky row
  // (k mod 24 in {0,8,16}) -> A-frag is a contiguous 16B slice of the image.
  const int p = w * 16 + lr;
  const int pe = p > 120 ? 120 : p;          // pad rows duplicate row 120
  const int oy = pe / 11, ox = pe - oy * 11;
  f32x4 acc[4] = {};
  #pragma unroll
  for (int ks = 0; ks < 6; ++ks) {
    const int k0 = ks * 32 + lg * 8;
    const int ky = k0 / 24, km = k0 - ky * 24;
    const bf16x8 a = *(const bf16x8*)&rgbL[(oy * 8 + ky) * LDR + ox * 24 + km];
    #pragma unroll
    for (int ni = 0; ni < 4; ++ni) {
      const bf16x8 bb = *(const bf16x8*)&BtL[(ni * 16 + lr) * LDB + k0];
      acc[ni] = __builtin_amdgcn_mfma_f32_16x16x32_bf16(a, bb, acc[ni], 0, 0, 0);
    }
  }
  __syncthreads();                           // rgbL reads done before aliasing

  // ---- epilogue: +bias, relu (+0 kills -0), store global + LDS bits
  float bias[4];
  #pragma unroll
  for (int ni = 0; ni < 4; ++ni) bias[ni] = bc[ni * 16 + lr];
  float* outB = out + (size_t)b * NPOS * NCH;
  #pragma unroll
  for (int rr = 0; rr < 4; ++rr) {
    const int ps = w * 16 + lg * 4 + rr;
    if (ps < NPOS) {
      #pragma unroll
      for (int ni = 0; ni < 4; ++ni) {
        const float v = fmaxf(acc[ni][rr] + bias[ni], 0.f) + 0.f;
        outB[ps * NCH + ni * 16 + lr] = v;
        fbits[ps * FST + ni * 16 + lr] = __float_as_uint(v);
      }
    }
  }
  __syncthreads();

  // ---- per-row signature (own-row hash, no atomics)
  if (tid < NPOS) {
    const uint4* fr = (const uint4*)&fbits[tid * FST];
    unsigned h = 0;
    #pragma unroll
    for (int q = 0; q < 16; ++q) {
      const uint4 v = fr[q];
      h ^= (v.x ^ (v.x >> 15)) * ((8u*q + 1u) * 0x9E3779B9u);
      h ^= (v.y ^ (v.y >> 15)) * ((8u*q + 3u) * 0x9E3779B9u);
      h ^= (v.z ^ (v.z >> 15)) * ((8u*q + 5u) * 0x9E3779B9u);
      h ^= (v.w ^ (v.w >> 15)) * ((8u*q + 7u) * 0x9E3779B9u);
    }
    sig[tid] = h;
  }
  __syncthreads();

  // ---- counts via signature match (exact verify on collision, ~never taken)
  int cnt = 0x7fffffff;
  if (tid < NPOS) {
    const unsigned si = sig[tid];
    int m = 0;
    for (int j = 0; j < NPOS; ++j) m += (sig[j] == si) ? 1 : 0;
    cnt = 1;
    if (m > 1) {
      cnt = 0;
      for (int j = 0; j < NPOS; ++j) {
        if (sig[j] == si) {
          int eq = 1;
          for (int c = 0; c < NCH; ++c) eq &= (fbits[tid*FST + c] == fbits[j*FST + c]);
          cnt += eq;
        }
      }
    }
    counts[tid] = cnt;
  }
  __syncthreads();

  // ---- kmin (block reduce over 8 waves)
  int km_ = cnt;
  #pragma unroll
  for (int off = 1; off < 64; off <<= 1) km_ = min(km_, __shfl_xor(km_, off, 64));
  if (lane == 0) redi[w] = km_;
  __syncthreads();
  int kmin = redi[0];
  #pragma unroll
  for (int q = 1; q < 8; ++q) kmin = min(kmin, redi[q]);

  // ---- allow rule: cum[c_i] = #{j: counts[j] <= c_i}; parallel, no histogram
  float wv = 0.f;
  if (tid < NPOS) {
    int cum = 0;
    for (int j = 0; j < NPOS; ++j) cum += (counts[j] <= cnt) ? 1 : 0;
    if (cum <= 36 || cnt == kmin) wv = 1.f / (float)cnt;   // K = int(0.3*121)
  }
  float s = wv;
  #pragma unroll
  for (int off = 1; off < 64; off <<= 1) s += __shfl_xor(s, off, 64);
  if (lane == 0) redf[w] = s;
  __syncthreads();
  float Z = redf[0];
  #pragma unroll
  for (int q = 1; q < 8; ++q) Z += redf[q];
  if (tid < NPOS) gout[(size_t)b * NPOS + tid] = wv / Z;
}

extern "C" void kernel_launch(void* const* d_in, const int* in_sizes, int n_in,
                              void* d_out, int out_size, void* d_ws, size_t ws_size,
                              hipStream_t stream) {
  const int*   rgb = (const int*)d_in[0];
  const float* Wc  = (const float*)d_in[1];
  const float* bc  = (const float*)d_in[2];
  float* out   = (float*)d_out;                        // vis_op: 30976 x 64
  float* guide = out + (size_t)NPATCH * NCH;           // guidance: 256 x 121

  fused<<<B_SZ, 512, 0, stream>>>(rgb, Wc, bc, out, guide);
}